// Round 8
// baseline (4343.146 us; speedup 1.0000x reference)
//
#include <hip/hip_runtime.h>

typedef __attribute__((ext_vector_type(8))) short bf16x8;   // 8 bf16 in 4 VGPRs
typedef __attribute__((ext_vector_type(4))) float f32x4;

#define NTT 512
#define NH  512
#define NIN 9
#define NO  3
#define MEMBERS 32    // WGs per group
#define MROWS   32    // batch rows per group
#define HPW     16    // hidden units per WG

__device__ __forceinline__ short f2bf(float f) {  // RNE fp32 -> bf16
  unsigned u = __builtin_bit_cast(unsigned, f);
  u = (u + 0x7fffu + ((u >> 16) & 1u)) >> 16;
  return (short)u;
}
__device__ __forceinline__ float bf2f(short s) {
  unsigned u = ((unsigned)(unsigned short)s) << 16;
  return __builtin_bit_cast(float, u);
}
__device__ __forceinline__ float sigf(float x) { return 1.f / (1.f + __expf(-x)); }
__device__ __forceinline__ float tanh_fast(float x) { return 1.f - 2.f / (1.f + __expf(2.f * x)); }

// ============================ TAGGED kernel =================================
// 256 WGs = 8 groups (32 batch rows) x 32 members (16 hidden each).
// h exchange: u32 word = bf16(h) | ((t+1)<<16); tag+payload atomically in one
// relaxed agent store. r8: poll retries are PER-WORD (straggler words reload
// individually; no slab re-read, no sleep, no extra barriers) and all
// t-invariant index math is hoisted out of the 512-step loop.
__global__ __launch_bounds__(256, 1) void lstm_tagged(
    const float* __restrict__ x, const float* __restrict__ W_ih,
    const float* __restrict__ W_hh, const float* __restrict__ b_ih,
    const float* __restrict__ b_hh, const float* __restrict__ W_fc,
    const float* __restrict__ b_fc, const int* __restrict__ horizon,
    float* __restrict__ out, unsigned* __restrict__ ws32) {
  const int tid  = threadIdx.x;
  const int bid  = blockIdx.x;
  const int g    = bid >> 5;   // group: batch rows [32g, 32g+32)
  const int w    = bid & 31;   // member: hidden [16w, 16w+16)
  const int wid  = tid >> 6;   // wave = gate index (i,f,g,o)
  const int lane = tid & 63;
  const int l15  = lane & 15;
  const int quad = lane >> 4;
  const int hl   = tid & 15;   // update mapping: hidden-local
  const int b0   = tid >> 4;   // update mapping: rows b0, b0+16
  const int hg   = w * HPW + hl;

  // ws (u32): tagged h dbuf [2][8 grp][32 rows][512] = 2 x 512 KB
  unsigned* tbuf0 = ws32;
  unsigned* tbuf1 = ws32 + 131072;

  __shared__ __align__(16) unsigned short hbuf[32][520];  // 1040B rows, b128-aligned
  __shared__ __align__(16) float gbuf[4][16][36];         // [gate][hl][b] 144B stride
  __shared__ float fcbuf[4][32][4];                       // [wave(K-split)][b][o]
  __shared__ float xbuf[32][NIN];
  __shared__ float xw[64][NIN];                           // W_ih rows (gate*16+hl)
  __shared__ float bsl[64];

  // ---- persistent B fragments: W_hh hi/lo (fp32-exact weights) ----
  bf16x8 Bhi[16], Blo[16];
#pragma unroll
  for (int kt = 0; kt < 16; ++kt) {
    bf16x8 vh, vl;
    const int row = wid * NH + w * HPW + l15;
#pragma unroll
    for (int j = 0; j < 8; ++j) {
      int k = kt * 32 + quad * 8 + j;
      float v = W_hh[(size_t)row * NH + k];
      short hi = f2bf(v);
      vh[j] = hi; vl[j] = f2bf(v - bf2f(hi));
    }
    Bhi[kt] = vh; Blo[kt] = vl;
  }
  // fc tile: wave wid covers K quarter [128*wid, +128)
  bf16x8 Fhi[4], Flo[4];
#pragma unroll
  for (int kk = 0; kk < 4; ++kk) {
    bf16x8 vh, vl;
#pragma unroll
    for (int j = 0; j < 8; ++j) {
      int k = (wid * 4 + kk) * 32 + quad * 8 + j;
      float v = (l15 < NO) ? W_fc[(size_t)l15 * NH + k] : 0.f;
      short hi = f2bf(v);
      vh[j] = hi; vl[j] = f2bf(v - bf2f(hi));
    }
    Fhi[kk] = vh; Flo[kk] = vl;
  }
  if (tid < 64) {  // x-path weights + biases, fp32 exact, in LDS
    int grow = (tid >> 4) * NH + w * HPW + (tid & 15);
    bsl[tid] = b_ih[grow] + b_hh[grow];
#pragma unroll
    for (int k = 0; k < NIN; ++k) xw[tid][k] = W_ih[grow * NIN + k];
  }
  for (int i = tid; i < 8320; i += 256) ((unsigned*)hbuf)[i] = 0u;  // h_0 = 0
  const float bfc0 = b_fc[0], bfc1 = b_fc[1], bfc2 = b_fc[2];
  const int hor = *horizon;

  // ---- hoisted t-invariant index math ----
  const int r0c = tid / NIN, k0c = tid - r0c * NIN;          // x slice part 0
  const int i1c = tid + 256;
  const int r1c = i1c / NIN, k1c = i1c - r1c * NIN;          // x slice part 1
  const bool x0ok = (r0c < MROWS), x1ok = (i1c < MROWS * NIN);
  const float* xp0 = x + (size_t)(g * MROWS + (x0ok ? r0c : 0)) * NTT * NIN + k0c;
  const float* xp1 = x + (size_t)(g * MROWS + (x1ok ? r1c : 0)) * NTT * NIN + k1c;
  const int ob = tid / NO, oo = tid - ob * NO;               // out write mapping
  const bool ook = (w == 0) && (tid < MROWS * NO);
  const float obias = (oo == 0) ? bfc0 : (oo == 1) ? bfc1 : bfc2;
  float* op = out + ((size_t)(g * MROWS + ob) * NTT) * NO + oo;  // + t*NO per step
  __syncthreads();

  float cst[2] = {0.f, 0.f};
  int tmod = 0;

  for (int t = 0; t <= NTT; ++t) {
    // x_t slice: issue global loads NOW (regs), write LDS after MFMA.
    float xv0 = 0.f, xv1 = 0.f;
    if (t < NTT) {
      if (x0ok) xv0 = xp0[t * NIN];
      if (x1ok) xv1 = xp1[t * NIN];
    }

    // ---- MFMA: this gate's 16 cols over full K, both M-tiles; fc K-quarter ----
    f32x4 z4 = {0.f, 0.f, 0.f, 0.f};
    f32x4 accg[2] = {z4, z4}, accf[2] = {z4, z4};
#pragma unroll
    for (int kt = 0; kt < 16; ++kt) {
      bf16x8 a0 = *(const bf16x8*)&hbuf[l15][kt * 32 + quad * 8];
      bf16x8 a1 = *(const bf16x8*)&hbuf[16 + l15][kt * 32 + quad * 8];
      accg[0] = __builtin_amdgcn_mfma_f32_16x16x32_bf16(a0, Bhi[kt], accg[0], 0, 0, 0);
      accg[1] = __builtin_amdgcn_mfma_f32_16x16x32_bf16(a1, Bhi[kt], accg[1], 0, 0, 0);
      accg[0] = __builtin_amdgcn_mfma_f32_16x16x32_bf16(a0, Blo[kt], accg[0], 0, 0, 0);
      accg[1] = __builtin_amdgcn_mfma_f32_16x16x32_bf16(a1, Blo[kt], accg[1], 0, 0, 0);
      if ((kt >> 2) == wid) {
        int kk = kt & 3;
        accf[0] = __builtin_amdgcn_mfma_f32_16x16x32_bf16(a0, Fhi[kk], accf[0], 0, 0, 0);
        accf[1] = __builtin_amdgcn_mfma_f32_16x16x32_bf16(a1, Fhi[kk], accf[1], 0, 0, 0);
        accf[0] = __builtin_amdgcn_mfma_f32_16x16x32_bf16(a0, Flo[kk], accf[0], 0, 0, 0);
        accf[1] = __builtin_amdgcn_mfma_f32_16x16x32_bf16(a1, Flo[kk], accf[1], 0, 0, 0);
      }
    }
    // stage: D row(b) = mt*16 + quad*4 + r, col = l15
#pragma unroll
    for (int mt = 0; mt < 2; ++mt)
      *(f32x4*)&gbuf[wid][l15][mt * 16 + quad * 4] = accg[mt];
    if (l15 < NO) {
#pragma unroll
      for (int mt = 0; mt < 2; ++mt)
#pragma unroll
        for (int r = 0; r < 4; ++r) fcbuf[wid][mt * 16 + quad * 4 + r][l15] = accf[mt][r];
    }
    if (t < NTT) {
      if (x0ok) xbuf[r0c][k0c] = xv0;
      if (x1ok) xbuf[r1c][k1c] = xv1;
    }
    __syncthreads();

    if (t == NTT) {  // final fc only
      if (ook)
        op[(t - 1) * NO] =
            obias + fcbuf[0][ob][oo] + fcbuf[1][ob][oo] + fcbuf[2][ob][oo] + fcbuf[3][ob][oo];
      break;
    }

    const bool raw = (t < 5) || (tmod == 0);
    const unsigned tg = (unsigned)(t + 1);
    unsigned* dst = ((t & 1) ? tbuf1 : tbuf0) + (size_t)g * 16384;  // u32 slab

    // ---- cell update: thread owns (b0, hl) and (b0+16, hl) ----
#pragma unroll
    for (int e = 0; e < 2; ++e) {
      int b = b0 + 16 * e;
      float xin[NIN];
#pragma unroll
      for (int k = 0; k < NIN; ++k) xin[k] = xbuf[b][k];
      if (!raw) {
        xin[0] = bfc0 + fcbuf[0][b][0] + fcbuf[1][b][0] + fcbuf[2][b][0] + fcbuf[3][b][0];
        xin[1] = bfc1 + fcbuf[0][b][1] + fcbuf[1][b][1] + fcbuf[2][b][1] + fcbuf[3][b][1];
        xin[2] = bfc2 + fcbuf[0][b][2] + fcbuf[1][b][2] + fcbuf[2][b][2] + fcbuf[3][b][2];
      }
      float gv[4];
#pragma unroll
      for (int gg = 0; gg < 4; ++gg) {
        int r = gg * 16 + hl;
        float s = bsl[r] + gbuf[gg][hl][b];
#pragma unroll
        for (int k = 0; k < NIN; ++k) s += xin[k] * xw[r][k];
        gv[gg] = s;
      }
      float cn = sigf(gv[1]) * cst[e] + sigf(gv[0]) * tanh_fast(gv[2]);
      cst[e] = cn;
      float hn = sigf(gv[3]) * tanh_fast(cn);
      // tagged store: payload+tag in ONE u32 -> atomic consistency for free
      unsigned word = (unsigned)(unsigned short)f2bf(hn) | (tg << 16);
      __hip_atomic_store(&dst[(size_t)b * NH + hg], word,
                         __ATOMIC_RELAXED, __HIP_MEMORY_SCOPE_AGENT);
    }

    // out[t-1]: member 0 writes (off the exchange critical path)
    if (ook && t > 0)
      op[(t - 1) * NO] =
          obias + fcbuf[0][ob][oo] + fcbuf[1][ob][oo] + fcbuf[2][ob][oo] + fcbuf[3][ob][oo];

    // ---- exchange: one cooperative slab read; PER-WORD straggler retry ----
    {
      const unsigned long long* src =
          (const unsigned long long*)(((t & 1) ? tbuf1 : tbuf0) + (size_t)g * 16384);
      const unsigned long long pat =
          ((unsigned long long)tg << 16) | ((unsigned long long)tg << 48);
      unsigned* hb32 = (unsigned*)hbuf;
#pragma unroll
      for (int half = 0; half < 2; ++half) {
        unsigned long long v[16];
#pragma unroll
        for (int j = 0; j < 16; ++j)
          v[j] = __hip_atomic_load(src + tid + 256 * (half * 16 + j),
                                   __ATOMIC_RELAXED, __HIP_MEMORY_SCOPE_AGENT);
#pragma unroll
        for (int j = 0; j < 16; ++j) {
          const int q = tid + 256 * (half * 16 + j);
          while ((v[j] ^ pat) & 0xFFFF0000FFFF0000ULL)   // straggler: reload THIS word
            v[j] = __hip_atomic_load(src + q, __ATOMIC_RELAXED,
                                     __HIP_MEMORY_SCOPE_AGENT);
          hb32[(q >> 8) * 260 + (q & 255)] =
              (unsigned)(v[j] & 0xFFFFu) | ((unsigned)(v[j] >> 32) << 16);
        }
      }
      __syncthreads();
    }
    ++tmod; if (tmod == hor) tmod = 0;
  }
}

// ====================== FALLBACK kernel (r4 verbatim) =======================
__global__ __launch_bounds__(256, 1) void lstm_fallback(
    const float* __restrict__ x, const float* __restrict__ W_ih,
    const float* __restrict__ W_hh, const float* __restrict__ b_ih,
    const float* __restrict__ b_hh, const float* __restrict__ W_fc,
    const float* __restrict__ b_fc, const int* __restrict__ horizon,
    float* __restrict__ out, unsigned short* __restrict__ ws) {
  const int tid  = threadIdx.x;
  const int bid  = blockIdx.x;
  const int g    = bid >> 5;
  const int w    = bid & 31;
  const int wid  = tid >> 6;
  const int lane = tid & 63;
  const int l15  = lane & 15;
  const int quad = lane >> 4;
  const int hl   = tid & 15;
  const int b0   = tid >> 4;

  unsigned short* buf0 = ws;
  unsigned short* buf1 = ws + 131072;
  int* fl = (int*)(ws + 262144) + g * MEMBERS;

  __shared__ __align__(16) unsigned short hbuf[32][520];
  __shared__ __align__(16) float gbuf[4][16][36];
  __shared__ float fcbuf[4][32][4];
  __shared__ float xbuf[32][NIN];
  __shared__ float xw[64][NIN];
  __shared__ float bsl[64];

  bf16x8 Bhi[16], Blo[16];
#pragma unroll
  for (int kt = 0; kt < 16; ++kt) {
    bf16x8 vh, vl;
    const int row = wid * NH + w * HPW + l15;
#pragma unroll
    for (int j = 0; j < 8; ++j) {
      int k = kt * 32 + quad * 8 + j;
      float v = W_hh[(size_t)row * NH + k];
      short hi = f2bf(v);
      vh[j] = hi; vl[j] = f2bf(v - bf2f(hi));
    }
    Bhi[kt] = vh; Blo[kt] = vl;
  }
  bf16x8 Fhi[4], Flo[4];
#pragma unroll
  for (int kk = 0; kk < 4; ++kk) {
    bf16x8 vh, vl;
#pragma unroll
    for (int j = 0; j < 8; ++j) {
      int k = (wid * 4 + kk) * 32 + quad * 8 + j;
      float v = (l15 < NO) ? W_fc[(size_t)l15 * NH + k] : 0.f;
      short hi = f2bf(v);
      vh[j] = hi; vl[j] = f2bf(v - bf2f(hi));
    }
    Fhi[kk] = vh; Flo[kk] = vl;
  }
  if (tid < 64) {
    int grow = (tid >> 4) * NH + w * HPW + (tid & 15);
    bsl[tid] = b_ih[grow] + b_hh[grow];
#pragma unroll
    for (int k = 0; k < NIN; ++k) xw[tid][k] = W_ih[grow * NIN + k];
  }
  for (int i = tid; i < 8320; i += 256) ((unsigned*)hbuf)[i] = 0u;
  const float bfc0 = b_fc[0], bfc1 = b_fc[1], bfc2 = b_fc[2];
  const int hor = *horizon;
  __syncthreads();

  float cst[2] = {0.f, 0.f};
  int tmod = 0;

  for (int t = 0; t <= NTT; ++t) {
    float xv0 = 0.f, xv1 = 0.f;
    int r0 = 0, k0 = 0, r1 = 0, k1 = 0;
    if (t < NTT) {
      r0 = tid / NIN; k0 = tid - r0 * NIN;
      if (r0 < MROWS) xv0 = x[((size_t)(g * MROWS + r0) * NTT + t) * NIN + k0];
      int i1 = tid + 256;
      r1 = i1 / NIN; k1 = i1 - r1 * NIN;
      if (i1 < MROWS * NIN) xv1 = x[((size_t)(g * MROWS + r1) * NTT + t) * NIN + k1];
    }
    f32x4 z4 = {0.f, 0.f, 0.f, 0.f};
    f32x4 accg[2] = {z4, z4}, accf[2] = {z4, z4};
#pragma unroll
    for (int kt = 0; kt < 16; ++kt) {
      bf16x8 a0 = *(const bf16x8*)&hbuf[l15][kt * 32 + quad * 8];
      bf16x8 a1 = *(const bf16x8*)&hbuf[16 + l15][kt * 32 + quad * 8];
      accg[0] = __builtin_amdgcn_mfma_f32_16x16x32_bf16(a0, Bhi[kt], accg[0], 0, 0, 0);
      accg[1] = __builtin_amdgcn_mfma_f32_16x16x32_bf16(a1, Bhi[kt], accg[1], 0, 0, 0);
      accg[0] = __builtin_amdgcn_mfma_f32_16x16x32_bf16(a0, Blo[kt], accg[0], 0, 0, 0);
      accg[1] = __builtin_amdgcn_mfma_f32_16x16x32_bf16(a1, Blo[kt], accg[1], 0, 0, 0);
      if ((kt >> 2) == wid) {
        int kk = kt & 3;
        accf[0] = __builtin_amdgcn_mfma_f32_16x16x32_bf16(a0, Fhi[kk], accf[0], 0, 0, 0);
        accf[1] = __builtin_amdgcn_mfma_f32_16x16x32_bf16(a1, Fhi[kk], accf[1], 0, 0, 0);
        accf[0] = __builtin_amdgcn_mfma_f32_16x16x32_bf16(a0, Flo[kk], accf[0], 0, 0, 0);
        accf[1] = __builtin_amdgcn_mfma_f32_16x16x32_bf16(a1, Flo[kk], accf[1], 0, 0, 0);
      }
    }
#pragma unroll
    for (int mt = 0; mt < 2; ++mt)
      *(f32x4*)&gbuf[wid][l15][mt * 16 + quad * 4] = accg[mt];
    if (l15 < NO) {
#pragma unroll
      for (int mt = 0; mt < 2; ++mt)
#pragma unroll
        for (int r = 0; r < 4; ++r) fcbuf[wid][mt * 16 + quad * 4 + r][l15] = accf[mt][r];
    }
    if (t < NTT) {
      if (r0 < MROWS) xbuf[r0][k0] = xv0;
      if (tid < MROWS * NIN - 256) xbuf[r1][k1] = xv1;
    }
    __syncthreads();

    if (t == NTT) {
      if (w == 0 && tid < MROWS * NO) {
        int b = tid / NO, o = tid - b * NO;
        float bo = (o == 0) ? bfc0 : (o == 1) ? bfc1 : bfc2;
        out[((size_t)(g * MROWS + b) * NTT + (t - 1)) * NO + o] =
            bo + fcbuf[0][b][o] + fcbuf[1][b][o] + fcbuf[2][b][o] + fcbuf[3][b][o];
      }
      break;
    }

    const bool raw = (t < 5) || (tmod == 0);
    unsigned long long* nxt64 =
        (unsigned long long*)(((t & 1) ? buf1 : buf0) + (size_t)g * (MROWS * NH));
#pragma unroll
    for (int e = 0; e < 2; ++e) {
      int b = b0 + 16 * e;
      float xin[NIN];
#pragma unroll
      for (int k = 0; k < NIN; ++k) xin[k] = xbuf[b][k];
      if (!raw) {
        xin[0] = bfc0 + fcbuf[0][b][0] + fcbuf[1][b][0] + fcbuf[2][b][0] + fcbuf[3][b][0];
        xin[1] = bfc1 + fcbuf[0][b][1] + fcbuf[1][b][1] + fcbuf[2][b][1] + fcbuf[3][b][1];
        xin[2] = bfc2 + fcbuf[0][b][2] + fcbuf[1][b][2] + fcbuf[2][b][2] + fcbuf[3][b][2];
      }
      float gv[4];
#pragma unroll
      for (int gg = 0; gg < 4; ++gg) {
        int r = gg * 16 + hl;
        float s = bsl[r] + gbuf[gg][hl][b];
#pragma unroll
        for (int k = 0; k < NIN; ++k) s += xin[k] * xw[r][k];
        gv[gg] = s;
      }
      float cn = sigf(gv[1]) * cst[e] + sigf(gv[0]) * tanh_fast(gv[2]);
      cst[e] = cn;
      float hn = sigf(gv[3]) * tanh_fast(cn);
      unsigned hb16 = (unsigned)(unsigned short)f2bf(hn);
      unsigned pair = hb16 | ((unsigned)__shfl_xor((int)hb16, 1, 64) << 16);
      unsigned long long v64 =
          (unsigned long long)pair |
          ((unsigned long long)(unsigned)__shfl_xor((int)pair, 2, 64) << 32);
      if ((hl & 3) == 0)
        __hip_atomic_store(&nxt64[(size_t)b * 128 + w * 4 + (hl >> 2)], v64,
                           __ATOMIC_RELAXED, __HIP_MEMORY_SCOPE_AGENT);
    }
    asm volatile("s_waitcnt vmcnt(0)" ::: "memory");
    __syncthreads();

    if (tid == 0)
      __hip_atomic_store(&fl[w], t + 1, __ATOMIC_RELAXED, __HIP_MEMORY_SCOPE_AGENT);
    if (w == 0 && t > 0 && tid < MROWS * NO) {
      int b = tid / NO, o = tid - b * NO;
      float bo = (o == 0) ? bfc0 : (o == 1) ? bfc1 : bfc2;
      out[((size_t)(g * MROWS + b) * NTT + (t - 1)) * NO + o] =
          bo + fcbuf[0][b][o] + fcbuf[1][b][o] + fcbuf[2][b][o] + fcbuf[3][b][o];
    }
    if (tid < MEMBERS) {
      while (__hip_atomic_load(&fl[tid], __ATOMIC_RELAXED,
                               __HIP_MEMORY_SCOPE_AGENT) < t + 1)
        __builtin_amdgcn_s_sleep(1);
    }
    __syncthreads();

    const unsigned long long* src =
        (const unsigned long long*)(((t & 1) ? buf1 : buf0) + (size_t)g * (MROWS * NH));
#pragma unroll
    for (int j = 0; j < 16; ++j) {
      int idx = tid + 256 * j;
      unsigned long long v =
          __hip_atomic_load(src + idx, __ATOMIC_RELAXED, __HIP_MEMORY_SCOPE_AGENT);
      *(unsigned long long*)&hbuf[idx >> 7][(idx & 127) * 4] = v;
    }
    __syncthreads();
    ++tmod; if (tmod == hor) tmod = 0;
  }
}

extern "C" void kernel_launch(void* const* d_in, const int* in_sizes, int n_in,
                              void* d_out, int out_size, void* d_ws, size_t ws_size,
                              hipStream_t stream) {
  (void)in_sizes; (void)n_in; (void)out_size;
  const float* x    = (const float*)d_in[0];
  const float* W_ih = (const float*)d_in[1];
  const float* W_hh = (const float*)d_in[2];
  const float* b_ih = (const float*)d_in[3];
  const float* b_hh = (const float*)d_in[4];
  const float* W_fc = (const float*)d_in[5];
  const float* b_fc = (const float*)d_in[6];
  const int*   hor  = (const int*)d_in[7];
  if (ws_size >= (size_t)1048576) {
    lstm_tagged<<<dim3(256), dim3(256), 0, stream>>>(
        x, W_ih, W_hh, b_ih, b_hh, W_fc, b_fc, hor,
        (float*)d_out, (unsigned*)d_ws);
  } else {
    lstm_fallback<<<dim3(256), dim3(256), 0, stream>>>(
        x, W_ih, W_hh, b_ih, b_hh, W_fc, b_fc, hor,
        (float*)d_out, (unsigned short*)d_ws);
  }
}

// Round 9
// 3093.839 us; speedup vs baseline: 1.4038x; 1.4038x over previous
//
#include <hip/hip_runtime.h>

typedef __attribute__((ext_vector_type(8))) short bf16x8;   // 8 bf16 in 4 VGPRs
typedef __attribute__((ext_vector_type(4))) float f32x4;

#define NTT 512
#define NH  512
#define NIN 9
#define NO  3
#define MEMBERS 32    // WGs per group
#define MROWS   32    // batch rows per group
#define HPW     16    // hidden units per WG

__device__ __forceinline__ short f2bf(float f) {  // RNE fp32 -> bf16
  unsigned u = __builtin_bit_cast(unsigned, f);
  u = (u + 0x7fffu + ((u >> 16) & 1u)) >> 16;
  return (short)u;
}
__device__ __forceinline__ float bf2f(short s) {
  unsigned u = ((unsigned)(unsigned short)s) << 16;
  return __builtin_bit_cast(float, u);
}
__device__ __forceinline__ float sigf(float x) { return 1.f / (1.f + __expf(-x)); }
__device__ __forceinline__ float tanh_fast(float x) { return 1.f - 2.f / (1.f + __expf(2.f * x)); }

// ============================ TAGGED kernel =================================
// 256 WGs = 8 groups (32 batch rows) x 32 members (16 hidden each).
// h exchange: u32 word = bf16(h) | ((t+1)<<16); tag+payload atomic in one
// relaxed agent store. r9 poll: ALL 32 slab loads issued before any check
// (one latency exposure, not 4 serialized rounds as in r7); stragglers
// retried as mask-driven BATCHES of independent loads (not r8's serial
// dependent per-word spin). One barrier at the end.
__global__ __launch_bounds__(256, 1) void lstm_tagged(
    const float* __restrict__ x, const float* __restrict__ W_ih,
    const float* __restrict__ W_hh, const float* __restrict__ b_ih,
    const float* __restrict__ b_hh, const float* __restrict__ W_fc,
    const float* __restrict__ b_fc, const int* __restrict__ horizon,
    float* __restrict__ out, unsigned* __restrict__ ws32) {
  const int tid  = threadIdx.x;
  const int bid  = blockIdx.x;
  const int g    = bid >> 5;   // group: batch rows [32g, 32g+32)
  const int w    = bid & 31;   // member: hidden [16w, 16w+16)
  const int wid  = tid >> 6;   // wave = gate index (i,f,g,o)
  const int lane = tid & 63;
  const int l15  = lane & 15;
  const int quad = lane >> 4;
  const int hl   = tid & 15;   // update mapping: hidden-local
  const int b0   = tid >> 4;   // update mapping: rows b0, b0+16
  const int hg   = w * HPW + hl;

  // ws (u32): tagged h dbuf [2][8 grp][32 rows][512] = 2 x 512 KB
  unsigned* tbuf0 = ws32;
  unsigned* tbuf1 = ws32 + 131072;

  __shared__ __align__(16) unsigned short hbuf[32][520];  // 1040B rows, b128-aligned
  __shared__ __align__(16) float gbuf[4][16][36];         // [gate][hl][b] 144B stride
  __shared__ float fcbuf[4][32][4];                       // [wave(K-split)][b][o]
  __shared__ float xbuf[32][NIN];
  __shared__ float xw[64][NIN];                           // W_ih rows (gate*16+hl)
  __shared__ float bsl[64];

  // ---- persistent B fragments: W_hh hi/lo (fp32-exact weights) ----
  bf16x8 Bhi[16], Blo[16];
#pragma unroll
  for (int kt = 0; kt < 16; ++kt) {
    bf16x8 vh, vl;
    const int row = wid * NH + w * HPW + l15;
#pragma unroll
    for (int j = 0; j < 8; ++j) {
      int k = kt * 32 + quad * 8 + j;
      float v = W_hh[(size_t)row * NH + k];
      short hi = f2bf(v);
      vh[j] = hi; vl[j] = f2bf(v - bf2f(hi));
    }
    Bhi[kt] = vh; Blo[kt] = vl;
  }
  // fc tile: wave wid covers K quarter [128*wid, +128)
  bf16x8 Fhi[4], Flo[4];
#pragma unroll
  for (int kk = 0; kk < 4; ++kk) {
    bf16x8 vh, vl;
#pragma unroll
    for (int j = 0; j < 8; ++j) {
      int k = (wid * 4 + kk) * 32 + quad * 8 + j;
      float v = (l15 < NO) ? W_fc[(size_t)l15 * NH + k] : 0.f;
      short hi = f2bf(v);
      vh[j] = hi; vl[j] = f2bf(v - bf2f(hi));
    }
    Fhi[kk] = vh; Flo[kk] = vl;
  }
  if (tid < 64) {  // x-path weights + biases, fp32 exact, in LDS
    int grow = (tid >> 4) * NH + w * HPW + (tid & 15);
    bsl[tid] = b_ih[grow] + b_hh[grow];
#pragma unroll
    for (int k = 0; k < NIN; ++k) xw[tid][k] = W_ih[grow * NIN + k];
  }
  for (int i = tid; i < 8320; i += 256) ((unsigned*)hbuf)[i] = 0u;  // h_0 = 0
  const float bfc0 = b_fc[0], bfc1 = b_fc[1], bfc2 = b_fc[2];
  const int hor = *horizon;

  // ---- hoisted t-invariant index math ----
  const int r0c = tid / NIN, k0c = tid - r0c * NIN;          // x slice part 0
  const int i1c = tid + 256;
  const int r1c = i1c / NIN, k1c = i1c - r1c * NIN;          // x slice part 1
  const bool x0ok = (r0c < MROWS), x1ok = (i1c < MROWS * NIN);
  const float* xp0 = x + (size_t)(g * MROWS + (x0ok ? r0c : 0)) * NTT * NIN + k0c;
  const float* xp1 = x + (size_t)(g * MROWS + (x1ok ? r1c : 0)) * NTT * NIN + k1c;
  const int ob = tid / NO, oo = tid - ob * NO;               // out write mapping
  const bool ook = (w == 0) && (tid < MROWS * NO);
  const float obias = (oo == 0) ? bfc0 : (oo == 1) ? bfc1 : bfc2;
  float* op = out + ((size_t)(g * MROWS + ob) * NTT) * NO + oo;  // + t*NO per step
  __syncthreads();

  float cst[2] = {0.f, 0.f};
  int tmod = 0;

  for (int t = 0; t <= NTT; ++t) {
    // x_t slice: issue global loads NOW (regs), write LDS after MFMA.
    float xv0 = 0.f, xv1 = 0.f;
    if (t < NTT) {
      if (x0ok) xv0 = xp0[t * NIN];
      if (x1ok) xv1 = xp1[t * NIN];
    }

    // ---- MFMA: this gate's 16 cols over full K, both M-tiles; fc K-quarter ----
    f32x4 z4 = {0.f, 0.f, 0.f, 0.f};
    f32x4 accg[2] = {z4, z4}, accf[2] = {z4, z4};
#pragma unroll
    for (int kt = 0; kt < 16; ++kt) {
      bf16x8 a0 = *(const bf16x8*)&hbuf[l15][kt * 32 + quad * 8];
      bf16x8 a1 = *(const bf16x8*)&hbuf[16 + l15][kt * 32 + quad * 8];
      accg[0] = __builtin_amdgcn_mfma_f32_16x16x32_bf16(a0, Bhi[kt], accg[0], 0, 0, 0);
      accg[1] = __builtin_amdgcn_mfma_f32_16x16x32_bf16(a1, Bhi[kt], accg[1], 0, 0, 0);
      accg[0] = __builtin_amdgcn_mfma_f32_16x16x32_bf16(a0, Blo[kt], accg[0], 0, 0, 0);
      accg[1] = __builtin_amdgcn_mfma_f32_16x16x32_bf16(a1, Blo[kt], accg[1], 0, 0, 0);
      if ((kt >> 2) == wid) {
        int kk = kt & 3;
        accf[0] = __builtin_amdgcn_mfma_f32_16x16x32_bf16(a0, Fhi[kk], accf[0], 0, 0, 0);
        accf[1] = __builtin_amdgcn_mfma_f32_16x16x32_bf16(a1, Fhi[kk], accf[1], 0, 0, 0);
        accf[0] = __builtin_amdgcn_mfma_f32_16x16x32_bf16(a0, Flo[kk], accf[0], 0, 0, 0);
        accf[1] = __builtin_amdgcn_mfma_f32_16x16x32_bf16(a1, Flo[kk], accf[1], 0, 0, 0);
      }
    }
    // stage: D row(b) = mt*16 + quad*4 + r, col = l15
#pragma unroll
    for (int mt = 0; mt < 2; ++mt)
      *(f32x4*)&gbuf[wid][l15][mt * 16 + quad * 4] = accg[mt];
    if (l15 < NO) {
#pragma unroll
      for (int mt = 0; mt < 2; ++mt)
#pragma unroll
        for (int r = 0; r < 4; ++r) fcbuf[wid][mt * 16 + quad * 4 + r][l15] = accf[mt][r];
    }
    if (t < NTT) {
      if (x0ok) xbuf[r0c][k0c] = xv0;
      if (x1ok) xbuf[r1c][k1c] = xv1;
    }
    __syncthreads();

    if (t == NTT) {  // final fc only
      if (ook)
        op[(t - 1) * NO] =
            obias + fcbuf[0][ob][oo] + fcbuf[1][ob][oo] + fcbuf[2][ob][oo] + fcbuf[3][ob][oo];
      break;
    }

    const bool raw = (t < 5) || (tmod == 0);
    const unsigned tg = (unsigned)(t + 1);
    unsigned* dst = ((t & 1) ? tbuf1 : tbuf0) + (size_t)g * 16384;  // u32 slab

    // ---- cell update: thread owns (b0, hl) and (b0+16, hl) ----
#pragma unroll
    for (int e = 0; e < 2; ++e) {
      int b = b0 + 16 * e;
      float xin[NIN];
#pragma unroll
      for (int k = 0; k < NIN; ++k) xin[k] = xbuf[b][k];
      if (!raw) {
        xin[0] = bfc0 + fcbuf[0][b][0] + fcbuf[1][b][0] + fcbuf[2][b][0] + fcbuf[3][b][0];
        xin[1] = bfc1 + fcbuf[0][b][1] + fcbuf[1][b][1] + fcbuf[2][b][1] + fcbuf[3][b][1];
        xin[2] = bfc2 + fcbuf[0][b][2] + fcbuf[1][b][2] + fcbuf[2][b][2] + fcbuf[3][b][2];
      }
      float gv[4];
#pragma unroll
      for (int gg = 0; gg < 4; ++gg) {
        int r = gg * 16 + hl;
        float s = bsl[r] + gbuf[gg][hl][b];
#pragma unroll
        for (int k = 0; k < NIN; ++k) s += xin[k] * xw[r][k];
        gv[gg] = s;
      }
      float cn = sigf(gv[1]) * cst[e] + sigf(gv[0]) * tanh_fast(gv[2]);
      cst[e] = cn;
      float hn = sigf(gv[3]) * tanh_fast(cn);
      // tagged store: payload+tag in ONE u32 -> atomic consistency for free
      unsigned word = (unsigned)(unsigned short)f2bf(hn) | (tg << 16);
      __hip_atomic_store(&dst[(size_t)b * NH + hg], word,
                         __ATOMIC_RELAXED, __HIP_MEMORY_SCOPE_AGENT);
    }

    // out[t-1]: member 0 writes (off the exchange critical path)
    if (ook && t > 0)
      op[(t - 1) * NO] =
          obias + fcbuf[0][ob][oo] + fcbuf[1][ob][oo] + fcbuf[2][ob][oo] + fcbuf[3][ob][oo];

    // ---- exchange: all 32 loads in flight BEFORE any check; batched retry ----
    {
      const unsigned long long* src =
          (const unsigned long long*)(((t & 1) ? tbuf1 : tbuf0) + (size_t)g * 16384);
      const unsigned long long pat =
          ((unsigned long long)tg << 16) | ((unsigned long long)tg << 48);
      unsigned* hb32 = (unsigned*)hbuf;
      unsigned long long v[32];
#pragma unroll
      for (int j = 0; j < 32; ++j)   // one latency exposure, 32 loads in flight
        v[j] = __hip_atomic_load(src + tid + 256 * j,
                                 __ATOMIC_RELAXED, __HIP_MEMORY_SCOPE_AGENT);
      unsigned mask = 0u;
#pragma unroll
      for (int j = 0; j < 32; ++j)
        mask |= (((v[j] ^ pat) & 0xFFFF0000FFFF0000ULL) ? 1u : 0u) << j;
      while (__builtin_expect(mask != 0u, 0)) {
        // batched straggler reload: all failed words re-issued as independent loads
#pragma unroll
        for (int j = 0; j < 32; ++j)
          if (mask & (1u << j))
            v[j] = __hip_atomic_load(src + tid + 256 * j,
                                     __ATOMIC_RELAXED, __HIP_MEMORY_SCOPE_AGENT);
        unsigned m2 = 0u;
#pragma unroll
        for (int j = 0; j < 32; ++j)
          m2 |= (((v[j] ^ pat) & 0xFFFF0000FFFF0000ULL) ? 1u : 0u) << j;
        mask = m2;
      }
#pragma unroll
      for (int j = 0; j < 32; ++j) {
        const int q = tid + 256 * j;
        hb32[(q >> 8) * 260 + (q & 255)] =
            (unsigned)(v[j] & 0xFFFFu) | ((unsigned)(v[j] >> 32) << 16);
      }
      __syncthreads();
    }
    ++tmod; if (tmod == hor) tmod = 0;
  }
}

// ====================== FALLBACK kernel (r4 structure) ======================
__global__ __launch_bounds__(256, 1) void lstm_fallback(
    const float* __restrict__ x, const float* __restrict__ W_ih,
    const float* __restrict__ W_hh, const float* __restrict__ b_ih,
    const float* __restrict__ b_hh, const float* __restrict__ W_fc,
    const float* __restrict__ b_fc, const int* __restrict__ horizon,
    float* __restrict__ out, unsigned short* __restrict__ ws) {
  const int tid  = threadIdx.x;
  const int bid  = blockIdx.x;
  const int g    = bid >> 5;
  const int w    = bid & 31;
  const int wid  = tid >> 6;
  const int lane = tid & 63;
  const int l15  = lane & 15;
  const int quad = lane >> 4;
  const int hl   = tid & 15;
  const int b0   = tid >> 4;

  unsigned short* buf0 = ws;
  unsigned short* buf1 = ws + 131072;
  int* fl = (int*)(ws + 262144) + g * MEMBERS;

  __shared__ __align__(16) unsigned short hbuf[32][520];
  __shared__ __align__(16) float gbuf[4][16][36];
  __shared__ float fcbuf[4][32][4];
  __shared__ float xbuf[32][NIN];
  __shared__ float xw[64][NIN];
  __shared__ float bsl[64];

  bf16x8 Bhi[16], Blo[16];
#pragma unroll
  for (int kt = 0; kt < 16; ++kt) {
    bf16x8 vh, vl;
    const int row = wid * NH + w * HPW + l15;
#pragma unroll
    for (int j = 0; j < 8; ++j) {
      int k = kt * 32 + quad * 8 + j;
      float v = W_hh[(size_t)row * NH + k];
      short hi = f2bf(v);
      vh[j] = hi; vl[j] = f2bf(v - bf2f(hi));
    }
    Bhi[kt] = vh; Blo[kt] = vl;
  }
  bf16x8 Fhi[4], Flo[4];
#pragma unroll
  for (int kk = 0; kk < 4; ++kk) {
    bf16x8 vh, vl;
#pragma unroll
    for (int j = 0; j < 8; ++j) {
      int k = (wid * 4 + kk) * 32 + quad * 8 + j;
      float v = (l15 < NO) ? W_fc[(size_t)l15 * NH + k] : 0.f;
      short hi = f2bf(v);
      vh[j] = hi; vl[j] = f2bf(v - bf2f(hi));
    }
    Fhi[kk] = vh; Flo[kk] = vl;
  }
  if (tid < 64) {
    int grow = (tid >> 4) * NH + w * HPW + (tid & 15);
    bsl[tid] = b_ih[grow] + b_hh[grow];
#pragma unroll
    for (int k = 0; k < NIN; ++k) xw[tid][k] = W_ih[grow * NIN + k];
  }
  for (int i = tid; i < 8320; i += 256) ((unsigned*)hbuf)[i] = 0u;
  const float bfc0 = b_fc[0], bfc1 = b_fc[1], bfc2 = b_fc[2];
  const int hor = *horizon;
  __syncthreads();

  float cst[2] = {0.f, 0.f};
  int tmod = 0;

  for (int t = 0; t <= NTT; ++t) {
    float xv0 = 0.f, xv1 = 0.f;
    int r0 = 0, k0 = 0, r1 = 0, k1 = 0;
    if (t < NTT) {
      r0 = tid / NIN; k0 = tid - r0 * NIN;
      if (r0 < MROWS) xv0 = x[((size_t)(g * MROWS + r0) * NTT + t) * NIN + k0];
      int i1 = tid + 256;
      r1 = i1 / NIN; k1 = i1 - r1 * NIN;
      if (i1 < MROWS * NIN) xv1 = x[((size_t)(g * MROWS + r1) * NTT + t) * NIN + k1];
    }
    f32x4 z4 = {0.f, 0.f, 0.f, 0.f};
    f32x4 accg[2] = {z4, z4}, accf[2] = {z4, z4};
#pragma unroll
    for (int kt = 0; kt < 16; ++kt) {
      bf16x8 a0 = *(const bf16x8*)&hbuf[l15][kt * 32 + quad * 8];
      bf16x8 a1 = *(const bf16x8*)&hbuf[16 + l15][kt * 32 + quad * 8];
      accg[0] = __builtin_amdgcn_mfma_f32_16x16x32_bf16(a0, Bhi[kt], accg[0], 0, 0, 0);
      accg[1] = __builtin_amdgcn_mfma_f32_16x16x32_bf16(a1, Bhi[kt], accg[1], 0, 0, 0);
      accg[0] = __builtin_amdgcn_mfma_f32_16x16x32_bf16(a0, Blo[kt], accg[0], 0, 0, 0);
      accg[1] = __builtin_amdgcn_mfma_f32_16x16x32_bf16(a1, Blo[kt], accg[1], 0, 0, 0);
      if ((kt >> 2) == wid) {
        int kk = kt & 3;
        accf[0] = __builtin_amdgcn_mfma_f32_16x16x32_bf16(a0, Fhi[kk], accf[0], 0, 0, 0);
        accf[1] = __builtin_amdgcn_mfma_f32_16x16x32_bf16(a1, Fhi[kk], accf[1], 0, 0, 0);
        accf[0] = __builtin_amdgcn_mfma_f32_16x16x32_bf16(a0, Flo[kk], accf[0], 0, 0, 0);
        accf[1] = __builtin_amdgcn_mfma_f32_16x16x32_bf16(a1, Flo[kk], accf[1], 0, 0, 0);
      }
    }
#pragma unroll
    for (int mt = 0; mt < 2; ++mt)
      *(f32x4*)&gbuf[wid][l15][mt * 16 + quad * 4] = accg[mt];
    if (l15 < NO) {
#pragma unroll
      for (int mt = 0; mt < 2; ++mt)
#pragma unroll
        for (int r = 0; r < 4; ++r) fcbuf[wid][mt * 16 + quad * 4 + r][l15] = accf[mt][r];
    }
    if (t < NTT) {
      if (r0 < MROWS) xbuf[r0][k0] = xv0;
      if (tid < MROWS * NIN - 256) xbuf[r1][k1] = xv1;
    }
    __syncthreads();

    if (t == NTT) {
      if (w == 0 && tid < MROWS * NO) {
        int b = tid / NO, o = tid - b * NO;
        float bo = (o == 0) ? bfc0 : (o == 1) ? bfc1 : bfc2;
        out[((size_t)(g * MROWS + b) * NTT + (t - 1)) * NO + o] =
            bo + fcbuf[0][b][o] + fcbuf[1][b][o] + fcbuf[2][b][o] + fcbuf[3][b][o];
      }
      break;
    }

    const bool raw = (t < 5) || (tmod == 0);
    unsigned long long* nxt64 =
        (unsigned long long*)(((t & 1) ? buf1 : buf0) + (size_t)g * (MROWS * NH));
#pragma unroll
    for (int e = 0; e < 2; ++e) {
      int b = b0 + 16 * e;
      float xin[NIN];
#pragma unroll
      for (int k = 0; k < NIN; ++k) xin[k] = xbuf[b][k];
      if (!raw) {
        xin[0] = bfc0 + fcbuf[0][b][0] + fcbuf[1][b][0] + fcbuf[2][b][0] + fcbuf[3][b][0];
        xin[1] = bfc1 + fcbuf[0][b][1] + fcbuf[1][b][1] + fcbuf[2][b][1] + fcbuf[3][b][1];
        xin[2] = bfc2 + fcbuf[0][b][2] + fcbuf[1][b][2] + fcbuf[2][b][2] + fcbuf[3][b][2];
      }
      float gv[4];
#pragma unroll
      for (int gg = 0; gg < 4; ++gg) {
        int r = gg * 16 + hl;
        float s = bsl[r] + gbuf[gg][hl][b];
#pragma unroll
        for (int k = 0; k < NIN; ++k) s += xin[k] * xw[r][k];
        gv[gg] = s;
      }
      float cn = sigf(gv[1]) * cst[e] + sigf(gv[0]) * tanh_fast(gv[2]);
      cst[e] = cn;
      float hn = sigf(gv[3]) * tanh_fast(cn);
      unsigned hb16 = (unsigned)(unsigned short)f2bf(hn);
      unsigned pair = hb16 | ((unsigned)__shfl_xor((int)hb16, 1, 64) << 16);
      unsigned long long v64 =
          (unsigned long long)pair |
          ((unsigned long long)(unsigned)__shfl_xor((int)pair, 2, 64) << 32);
      if ((hl & 3) == 0)
        __hip_atomic_store(&nxt64[(size_t)b * 128 + w * 4 + (hl >> 2)], v64,
                           __ATOMIC_RELAXED, __HIP_MEMORY_SCOPE_AGENT);
    }
    asm volatile("s_waitcnt vmcnt(0)" ::: "memory");
    __syncthreads();

    if (tid == 0)
      __hip_atomic_store(&fl[w], t + 1, __ATOMIC_RELAXED, __HIP_MEMORY_SCOPE_AGENT);
    if (w == 0 && t > 0 && tid < MROWS * NO) {
      int b = tid / NO, o = tid - b * NO;
      float bo = (o == 0) ? bfc0 : (o == 1) ? bfc1 : bfc2;
      out[((size_t)(g * MROWS + b) * NTT + (t - 1)) * NO + o] =
          bo + fcbuf[0][b][o] + fcbuf[1][b][o] + fcbuf[2][b][o] + fcbuf[3][b][o];
    }
    if (tid < MEMBERS) {
      while (__hip_atomic_load(&fl[tid], __ATOMIC_RELAXED,
                               __HIP_MEMORY_SCOPE_AGENT) < t + 1)
        __builtin_amdgcn_s_sleep(1);
    }
    __syncthreads();

    const unsigned long long* src =
        (const unsigned long long*)(((t & 1) ? buf1 : buf0) + (size_t)g * (MROWS * NH));
#pragma unroll
    for (int j = 0; j < 16; ++j) {
      int idx = tid + 256 * j;
      unsigned long long v =
          __hip_atomic_load(src + idx, __ATOMIC_RELAXED, __HIP_MEMORY_SCOPE_AGENT);
      *(unsigned long long*)&hbuf[idx >> 7][(idx & 127) * 4] = v;
    }
    __syncthreads();
    ++tmod; if (tmod == hor) tmod = 0;
  }
}

extern "C" void kernel_launch(void* const* d_in, const int* in_sizes, int n_in,
                              void* d_out, int out_size, void* d_ws, size_t ws_size,
                              hipStream_t stream) {
  (void)in_sizes; (void)n_in; (void)out_size;
  const float* x    = (const float*)d_in[0];
  const float* W_ih = (const float*)d_in[1];
  const float* W_hh = (const float*)d_in[2];
  const float* b_ih = (const float*)d_in[3];
  const float* b_hh = (const float*)d_in[4];
  const float* W_fc = (const float*)d_in[5];
  const float* b_fc = (const float*)d_in[6];
  const int*   hor  = (const int*)d_in[7];
  if (ws_size >= (size_t)1048576) {
    lstm_tagged<<<dim3(256), dim3(256), 0, stream>>>(
        x, W_ih, W_hh, b_ih, b_hh, W_fc, b_fc, hor,
        (float*)d_out, (unsigned*)d_ws);
  } else {
    lstm_fallback<<<dim3(256), dim3(256), 0, stream>>>(
        x, W_ih, W_hh, b_ih, b_hh, W_fc, b_fc, hor,
        (float*)d_out, (unsigned short*)d_ws);
  }
}